// Round 5
// baseline (46364.050 us; speedup 1.0000x reference)
//
#include <hip/hip_runtime.h>
#include <math.h>

// ---------------------------------------------------------------------------
// Model constants
#define L_ENC 750
#define T_AUD 1500
#define DD    384
#define FF    1024
#define NHH   4
#define HDIM  96
#define VOCAB 60
#define T_TXT 256
#define BB    8

// ---- state offsets (floats, relative to ST = ws + O_ST) ----
#define S_HASR 0
#define S_ATT0 6000
#define S_ATT1 12000
#define S_HD0  18000
#define S_HD1  21072
#define S_ACTX 24144
#define S_SCTX 27216
#define S_GIA  33360
#define S_GHA  51360
#define S_GID  69360
#define S_GHD  78576
#define S_LACC 87792
#define S_VLA  87800
#define S_INVN 93800
#define S_FLG  94000   // 512 lines x 16 uints (arrive[0..255], go[256..511])
#define ST_SIZE 102200

static __device__ __forceinline__ float sigmf(float x){ return 1.f/(1.f + __expf(-x)); }

static __device__ __forceinline__ float bf2f(unsigned short u){
  union { unsigned u; float f; } c; c.u = ((unsigned)u) << 16; return c.f;
}
static __device__ __forceinline__ unsigned short f2bf(float f){
  unsigned u = __float_as_uint(f);
  unsigned r = (u + 0x7FFFu + ((u >> 16) & 1u)) >> 16;
  return (unsigned short)r;
}

// Coherence-point accessors for cross-block decode state (bypass L1/L2; no
// fences needed -> clean weight lines stay cached in L2 across phases).
static __device__ __forceinline__ float gload(const float* p){
  return __hip_atomic_load(p, __ATOMIC_RELAXED, __HIP_MEMORY_SCOPE_AGENT);
}
static __device__ __forceinline__ void gstore(float* p, float v){
  __hip_atomic_store(p, v, __ATOMIC_RELAXED, __HIP_MEMORY_SCOPE_AGENT);
}

// ---------------------------------------------------------------------------
// Generic tiled transpose: out[c*R + r] = in[r*ldin + c]
__global__ void transpose_k(const float* __restrict__ in, int ldin, int R, int C,
                            float* __restrict__ out){
  __shared__ float t[32][33];
  int c0 = blockIdx.x*32, r0 = blockIdx.y*32;
  int x = threadIdx.x, y = threadIdx.y;
  for (int i = y; i < 32; i += 8){
    int r = r0 + i, c = c0 + x;
    t[i][x] = (r < R && c < C) ? in[(size_t)r*ldin + c] : 0.f;
  }
  __syncthreads();
  for (int i = y; i < 32; i += 8){
    int c = c0 + i, r = r0 + x;
    if (c < C && r < R) out[(size_t)c*R + r] = t[x][i];
  }
}

// Transpose + convert to bf16, optionally batched over blockIdx.z
__global__ void transpose_bf16_k(const float* __restrict__ in, int ldin, int R, int C,
                                 unsigned short* __restrict__ out,
                                 size_t inBatch, size_t outBatch){
  __shared__ float t[32][33];
  int z = blockIdx.z;
  in  += (size_t)z*inBatch;
  out += (size_t)z*outBatch;
  int c0 = blockIdx.x*32, r0 = blockIdx.y*32;
  int x = threadIdx.x, y = threadIdx.y;
  for (int i = y; i < 32; i += 8){
    int r = r0 + i, c = c0 + x;
    t[i][x] = (r < R && c < C) ? in[(size_t)r*ldin + c] : 0.f;
  }
  __syncthreads();
  for (int i = y; i < 32; i += 8){
    int c = c0 + i, r = r0 + x;
    if (c < C && r < R) out[(size_t)c*R + r] = f2bf(t[x][i]);
  }
}

// Row-major fp32 -> bf16 copy of a column slice: out[r*C+c] = in[r*ldin+c]
__global__ __launch_bounds__(384) void convrow_k(const float* __restrict__ in, int ldin, int C,
                                                 unsigned short* __restrict__ out){
  int r = blockIdx.x, c = threadIdx.x;
  if (c < C) out[(size_t)r*C + c] = f2bf(in[(size_t)r*ldin + c]);
}

// K-transpose for encoder attention
__global__ void kt_k(const float* __restrict__ QKV, float* __restrict__ KT){
  __shared__ float t[32][33];
  int z = blockIdx.z; int b = z >> 2, h = z & 3;
  const float* in = QKV + (size_t)b*L_ENC*1152 + 384 + h*HDIM;
  float* out = KT + (size_t)z*HDIM*L_ENC;
  int c0 = blockIdx.x*32, r0 = blockIdx.y*32;
  int x = threadIdx.x, y = threadIdx.y;
  for (int i = y; i < 32; i += 8){
    int r = r0 + i, c = c0 + x;
    t[i][x] = (r < L_ENC && c < HDIM) ? in[(size_t)r*1152 + c] : 0.f;
  }
  __syncthreads();
  for (int i = y; i < 32; i += 8){
    int c = c0 + i, r = r0 + x;
    if (c < HDIM && r < L_ENC) out[(size_t)c*L_ENC + r] = t[x][i];
  }
}

// ---------------------------------------------------------------------------
// Generic fp32 GEMM: C[M,N] = act(A[M,K] @ W[N,K]^T + bias[N] (+ Res[M,N]))
template<int RELU, int HASRES, int BF16OUT = 0, int NOBIAS = 0>
__global__ __launch_bounds__(256) void gemm_k(
    const float* __restrict__ A, int lda, const float* __restrict__ W, int ldw,
    const float* __restrict__ bias, const float* __restrict__ Res,
    float* __restrict__ C, int ldc, int M, int N, int K)
{
  __shared__ __align__(16) float As[16][132];
  __shared__ __align__(16) float Ws[16][68];
  int tid = threadIdx.x;
  int row0 = blockIdx.y*128, col0 = blockIdx.x*64;
  int tx = tid & 15, ty = tid >> 4;
  int lr = tid >> 2, lk = (tid & 3)*4;
  float acc[8][4] = {};
  for (int k0 = 0; k0 < K; k0 += 16){
    float4 a0 = make_float4(0,0,0,0), a1 = make_float4(0,0,0,0), w0 = make_float4(0,0,0,0);
    int r0i = row0 + lr, r1i = row0 + 64 + lr, wri = col0 + lr;
    if (r0i < M) a0 = *(const float4*)(A + (size_t)r0i*lda + k0 + lk);
    if (r1i < M) a1 = *(const float4*)(A + (size_t)r1i*lda + k0 + lk);
    if (wri < N) w0 = *(const float4*)(W + (size_t)wri*ldw + k0 + lk);
    As[lk+0][lr] = a0.x; As[lk+1][lr] = a0.y; As[lk+2][lr] = a0.z; As[lk+3][lr] = a0.w;
    As[lk+0][64+lr] = a1.x; As[lk+1][64+lr] = a1.y; As[lk+2][64+lr] = a1.z; As[lk+3][64+lr] = a1.w;
    Ws[lk+0][lr] = w0.x; Ws[lk+1][lr] = w0.y; Ws[lk+2][lr] = w0.z; Ws[lk+3][lr] = w0.w;
    __syncthreads();
    #pragma unroll
    for (int k = 0; k < 16; k++){
      float4 b4 = *(const float4*)&Ws[k][tx*4];
      float4 a4 = *(const float4*)&As[k][ty*8];
      float4 a5 = *(const float4*)&As[k][ty*8+4];
      acc[0][0] += a4.x*b4.x; acc[0][1] += a4.x*b4.y; acc[0][2] += a4.x*b4.z; acc[0][3] += a4.x*b4.w;
      acc[1][0] += a4.y*b4.x; acc[1][1] += a4.y*b4.y; acc[1][2] += a4.y*b4.z; acc[1][3] += a4.y*b4.w;
      acc[2][0] += a4.z*b4.x; acc[2][1] += a4.z*b4.y; acc[2][2] += a4.z*b4.z; acc[2][3] += a4.z*b4.w;
      acc[3][0] += a4.w*b4.x; acc[3][1] += a4.w*b4.y; acc[3][2] += a4.w*b4.z; acc[3][3] += a4.w*b4.w;
      acc[4][0] += a5.x*b4.x; acc[4][1] += a5.x*b4.y; acc[4][2] += a5.x*b4.z; acc[4][3] += a5.x*b4.w;
      acc[5][0] += a5.y*b4.x; acc[5][1] += a5.y*b4.y; acc[5][2] += a5.y*b4.z; acc[5][3] += a5.y*b4.w;
      acc[6][0] += a5.z*b4.x; acc[6][1] += a5.z*b4.y; acc[6][2] += a5.z*b4.z; acc[6][3] += a5.z*b4.w;
      acc[7][0] += a5.w*b4.x; acc[7][1] += a5.w*b4.y; acc[7][2] += a5.w*b4.z; acc[7][3] += a5.w*b4.w;
    }
    __syncthreads();
  }
  #pragma unroll
  for (int ii = 0; ii < 8; ii++){
    int m = row0 + ty*8 + ii;
    if (m >= M) continue;
    #pragma unroll
    for (int jj = 0; jj < 4; jj++){
      int n = col0 + tx*4 + jj;
      if (n >= N) continue;
      float v = acc[ii][jj];
      if (!NOBIAS) v += bias[n];
      if (HASRES) v += Res[(size_t)m*ldc + n];
      if (RELU) v = fmaxf(v, 0.f);
      if (BF16OUT) ((unsigned short*)C)[(size_t)m*ldc + n] = f2bf(v);
      else C[(size_t)m*ldc + n] = v;
    }
  }
}

// ---------------------------------------------------------------------------
// im2col for conv1 (k=3, pad=1, stride=1)
__global__ void im2col1(const float* __restrict__ in, float* __restrict__ P){
  int t = blockIdx.x, b = blockIdx.y, i = threadIdx.x;
  if (i >= 240) return;
  int ic = i/3, kt = i - ic*3;
  int p = t + kt - 1;
  P[((size_t)(b*T_AUD + t))*240 + i] = (p >= 0 && p < T_AUD) ? in[((size_t)(b*80 + ic))*T_AUD + p] : 0.f;
}

// im2col for conv2 (k=3, pad=1, stride=2)
__global__ __launch_bounds__(384) void im2col2(const float* __restrict__ X1T, float* __restrict__ P){
  int t = blockIdx.x, b = blockIdx.y, ic = threadIdx.x;
  size_t ob = ((size_t)(b*L_ENC + t))*1152 + (size_t)ic*3;
  #pragma unroll
  for (int kt = 0; kt < 3; kt++){
    int p = 2*t + kt - 1;
    P[ob + kt] = (p >= 0 && p < T_AUD) ? X1T[((size_t)(b*T_AUD + p))*DD + ic] : 0.f;
  }
}

// ---------------------------------------------------------------------------
// LayerNorm in-place over rows of 384
__global__ __launch_bounds__(128) void ln_k(float* __restrict__ X, const float* __restrict__ g,
                                            const float* __restrict__ bt){
  int r = blockIdx.x, tid = threadIdx.x;
  float* p = X + (size_t)r*DD;
  float v0 = p[tid], v1 = p[tid+128], v2 = p[tid+256];
  __shared__ float red[128];
  red[tid] = v0+v1+v2; __syncthreads();
  for (int k = 64; k > 0; k >>= 1){ if (tid < k) red[tid] += red[tid+k]; __syncthreads(); }
  float m = red[0] * (1.f/384.f);
  __syncthreads();
  float d0 = v0-m, d1 = v1-m, d2 = v2-m;
  red[tid] = d0*d0 + d1*d1 + d2*d2; __syncthreads();
  for (int k = 64; k > 0; k >>= 1){ if (tid < k) red[tid] += red[tid+k]; __syncthreads(); }
  float rs = rsqrtf(red[0]*(1.f/384.f) + 1e-5f);
  p[tid]     = d0*rs*g[tid]     + bt[tid];
  p[tid+128] = d1*rs*g[tid+128] + bt[tid+128];
  p[tid+256] = d2*rs*g[tid+256] + bt[tid+256];
}

// ---------------------------------------------------------------------------
// Encoder attention, fused scores+softmax+AV.
__global__ __launch_bounds__(1024) void attn_enc(const float* __restrict__ QKV,
    const float* __restrict__ KT, float* __restrict__ ctx){
  int b = blockIdx.z, h = blockIdx.y, i0 = blockIdx.x*16;
  int tid = threadIdx.x, lane = tid & 63, wv = tid >> 6;
  __shared__ float q_s[16][96];
  __shared__ float p_s[16][752];
  __shared__ float den_s[16];
  for (int idx = tid; idx < 16*96; idx += 1024){
    int r2 = idx/96, c = idx - r2*96; int i = i0 + r2;
    q_s[r2][c] = (i < L_ENC) ? QKV[((size_t)(b*L_ENC + i))*1152 + h*HDIM + c]*0.10206207f : 0.f;
  }
  __syncthreads();
  int i = i0 + wv;
  const float* ktb = KT + ((size_t)(b*4 + h))*HDIM*L_ENC;
  if (i < L_ENC){
    float sr[12] = {0,0,0,0,0,0,0,0,0,0,0,0};
    for (int c = 0; c < 96; c++){
      float qc = q_s[wv][c];
      const float* kr = ktb + c*L_ENC + lane;
      #pragma unroll
      for (int jt = 0; jt < 12; jt++) sr[jt] += qc*kr[jt*64];
    }
    float mx = -1e30f;
    #pragma unroll
    for (int jt = 0; jt < 12; jt++){ if (lane + jt*64 < L_ENC) mx = fmaxf(mx, sr[jt]); }
    #pragma unroll
    for (int o = 32; o > 0; o >>= 1) mx = fmaxf(mx, __shfl_xor(mx, o));
    float den = 0.f;
    #pragma unroll
    for (int jt = 0; jt < 12; jt++){
      int j = lane + jt*64;
      if (j < L_ENC){ float e = __expf(sr[jt]-mx); p_s[wv][j] = e; den += e; }
    }
    #pragma unroll
    for (int o = 32; o > 0; o >>= 1) den += __shfl_xor(den, o);
    if (lane == 0) den_s[wv] = den;
  }
  __syncthreads();
  if (i < L_ENC){
    float idn = 1.f/den_s[wv];
    const float* vb = QKV + (size_t)b*L_ENC*1152 + 768 + h*HDIM;
    float a0 = 0.f, a1 = 0.f;
    for (int j = 0; j < L_ENC; j++){
      float pj = p_s[wv][j];
      const float* vr = vb + (size_t)j*1152;
      a0 += pj*vr[lane];
      if (lane < 32) a1 += pj*vr[lane + 64];
    }
    size_t ob = ((size_t)(b*L_ENC + i))*DD + h*HDIM;
    ctx[ob + lane] = a0*idn;
    if (lane < 32) ctx[ob + lane + 64] = a1*idn;
  }
}

// ---------------------------------------------------------------------------
// Decode precompute helpers
__global__ __launch_bounds__(384) void embed_k(const float* __restrict__ emb,
    const int* __restrict__ tgtA, float* __restrict__ E){
  int row = blockIdx.x; int t = row >> 3, b = row & 7;
  int tok = 0;
  if (t > 0){ int v = tgtA[b*T_TXT + t - 1]; tok = (v == -100) ? 0 : v; }
  E[(size_t)row*DD + threadIdx.x] = emb[(size_t)tok*DD + threadIdx.x];
}

__global__ __launch_bounds__(256) void vla_k(const float* __restrict__ EA,
    const float* __restrict__ lav, const float* __restrict__ lain, float* __restrict__ VLA){
  int row = blockIdx.x*4 + (threadIdx.x >> 6);
  int lane = threadIdx.x & 63;
  if (row >= BB*L_ENC) return;
  const float* p = EA + (size_t)row*DD;
  float s = 0.f;
  for (int d = lane; d < DD; d += 64) s += p[d]*lav[d];
  #pragma unroll
  for (int o = 32; o > 0; o >>= 1) s += __shfl_xor(s, o);
  if (lane == 0) VLA[row] = s + lain[2];
}

__global__ void invn_k(const float* __restrict__ inv, float* __restrict__ INVN){
  int row = blockIdx.x; int lane = threadIdx.x;
  float s = 0.f;
  for (int d = lane; d < DD; d += 64){ float v = inv[(size_t)row*DD + d]; s += v*v; }
  #pragma unroll
  for (int o = 32; o > 0; o >>= 1) s += __shfl_xor(s, o);
  if (lane == 0) INVN[row] = sqrtf(s);
}

// biasC[v] = AOB[v] + sum_d (H2AB[d]+D2AB[d])*AOW[v][d]
__global__ void biasc_k(const float* __restrict__ AOB, const float* __restrict__ H2AB,
                        const float* __restrict__ D2AB, const float* __restrict__ AOW,
                        float* __restrict__ biasC){
  int v = threadIdx.x; if (v >= VOCAB) return;
  float s = AOB[v];
  for (int d = 0; d < DD; d++) s += (H2AB[d] + D2AB[d])*AOW[(size_t)v*DD + d];
  biasC[v] = s;
}

// ---------------------------------------------------------------------------
// Fence-FREE grid barrier. Private polled lines; arrive/go use RELEASE stores
// (waitcnt + L2 writeback, NO invalidate) so clean weight lines stay in L2.
// All cross-block data goes through gload/gstore (coherence-point accesses).
__device__ __forceinline__ void gridbar(unsigned* flags, unsigned ep){
  __syncthreads();
  if (blockIdx.x == 0){
    int tid = threadIdx.x;
    if (tid > 0){
      while (__hip_atomic_load(&flags[tid*16], __ATOMIC_RELAXED, __HIP_MEMORY_SCOPE_AGENT) != ep)
        __builtin_amdgcn_s_sleep(1);
    }
    __syncthreads();
    if (tid > 0)
      __hip_atomic_store(&flags[(256 + tid)*16], ep, __ATOMIC_RELEASE, __HIP_MEMORY_SCOPE_AGENT);
    __syncthreads();
  } else {
    if (threadIdx.x == 0){
      __hip_atomic_store(&flags[blockIdx.x*16], ep, __ATOMIC_RELEASE, __HIP_MEMORY_SCOPE_AGENT);
      while (__hip_atomic_load(&flags[(256 + blockIdx.x)*16], __ATOMIC_RELAXED, __HIP_MEMORY_SCOPE_AGENT) != ep)
        __builtin_amdgcn_s_sleep(1);
    }
    __syncthreads();
  }
}

// GEMV for 8 batches: out[b][r] = sum_k bf16 W[k][r] * x[b][k] + extra
// x is cross-block state -> gload; out -> gstore. W/extra16/bias are read-only
// (normal cached loads, L2-resident).
__device__ __forceinline__ void gemv8(const unsigned short* __restrict__ W, int NR, int K,
    const float* __restrict__ x, const unsigned short* __restrict__ extra16, int emode,
    const float* __restrict__ bias, float* __restrict__ out, int vb, float* sm)
{
  int tid = threadIdx.x;
  float* xs = sm;
  float* pg = sm + K*8;
  for (int idx = tid; idx < 8*K; idx += 256){
    int b = idx / K, k = idx - b*K;
    xs[k*8 + b] = gload(x + idx);
  }
  __syncthreads();
  int rl = tid & 31, kp = tid >> 5;
  int r = vb*32 + rl;
  float a0=0,a1=0,a2=0,a3=0,a4=0,a5=0,a6=0,a7=0;
  if (r < NR){
    int kc = (K + 7) >> 3;
    int k0 = kp*kc, k1 = k0 + kc; if (k1 > K) k1 = K;
    const unsigned short* Wp = W + (size_t)k0*NR + r;
    for (int k = k0; k < k1; k++){
      float w = bf2f(*Wp); Wp += NR;
      const float4 v0 = *(const float4*)&xs[k*8];
      const float4 v1 = *(const float4*)&xs[k*8+4];
      a0 += w*v0.x; a1 += w*v0.y; a2 += w*v0.z; a3 += w*v0.w;
      a4 += w*v1.x; a5 += w*v1.y; a6 += w*v1.z; a7 += w*v1.w;
    }
  }
  float* pr = pg + (size_t)(kp*32 + rl)*8;
  pr[0]=a0; pr[1]=a1; pr[2]=a2; pr[3]=a3; pr[4]=a4; pr[5]=a5; pr[6]=a6; pr[7]=a7;
  __syncthreads();
  int b = tid >> 5, rr = tid & 31;
  int r2 = vb*32 + rr;
  if (r2 < NR){
    float s = 0.f;
    #pragma unroll
    for (int q = 0; q < 8; q++) s += pg[(size_t)(q*32 + rr)*8 + b];
    if (emode == 0) s += bf2f(extra16[(size_t)b*NR + r2]);
    else s += bias[r2];
    gstore(out + (size_t)b*NR + r2, s);
  }
  __syncthreads();
}

// ---------------------------------------------------------------------------
// Whole decode in one launch: 3 pipelined phases per step, 769 barriers total.
__global__ __launch_bounds__(256, 1) void decode_persist(
  const unsigned short* __restrict__ WA_I, const unsigned short* __restrict__ WA_H,
  const unsigned short* __restrict__ WD_IR, const unsigned short* __restrict__ WD_H,
  const unsigned short* __restrict__ EAT16, const unsigned short* __restrict__ EDT16,
  const unsigned short* __restrict__ AO16, const unsigned short* __restrict__ W1T16,
  const unsigned short* __restrict__ GEA16, const unsigned short* __restrict__ GED16,
  const float* __restrict__ SPKV, const float* __restrict__ BIASC,
  const float* __restrict__ ABHH, const float* __restrict__ DBHH,
  const float* __restrict__ LAQ, const float* __restrict__ LAK, const float* __restrict__ LAIB,
  const float* __restrict__ LAOW, const float* __restrict__ LAOB,
  const float* __restrict__ SPK, const int* __restrict__ TGTA, const int* __restrict__ TGTD,
  float* __restrict__ ST, float* __restrict__ out, unsigned* __restrict__ flags)
{
  __shared__ float sm[8064];
  __shared__ float red_s[256], scp_s[256], sc_s[8], beta_s[8];
  int blk = blockIdx.x, tid = threadIdx.x;
  unsigned ep = 0;
  float laqw = LAQ[0], laqb = LAIB[0], lakw = LAK[0], lakb = LAIB[1];
  float laow = LAOW[0], laob = LAOB[0];
  float* lacc = ST + S_LACC;

  // ---- Phase 0: init carried gate arrays for t=0 ----
  {
    int idx = blk*256 + tid;
    if (idx < 18000){
      gstore(ST + S_GIA + idx, bf2f(GEA16[idx]));   // GIA(0) = GEA(0) (ACTX=0)
      gstore(ST + S_GHA + idx, ABHH[idx % 2250]);   // GHA(0) = bias  (HASR=0)
    }
  }
  ep += 1; gridbar(flags, ep);

  for (int t = 0; t < T_TXT; t++){
    float* acur = ST + ((t & 1) ? S_ATT1 : S_ATT0);
    float* anxt = ST + ((t & 1) ? S_ATT0 : S_ATT1);
    float* hdc  = ST + ((t & 1) ? S_HD1 : S_HD0);
    float* hdn  = ST + ((t & 1) ? S_HD0 : S_HD1);

    // ---- Phase 1: h_asr GRU + rank-1 attention row  ||  GHD(t) gemv ----
    if (blk < 128){
      int b = blk >> 4, ch = blk & 15;
      int cs = ch*47, ce = cs + 47; if (ce > 750) ce = 750;
      float* kk = sm; float* vv = sm + 752;
      for (int j = tid; j < 750; j += 256){
        kk[j] = gload(acur + b*750 + j)*lakw + lakb;
        vv[j] = ST[S_VLA + b*750 + j];        // constant during decode
      }
      __syncthreads();
      int lane = tid & 63, wv = tid >> 6;
      const float* GIAb = ST + S_GIA + b*2250;
      const float* GHAb = ST + S_GHA + b*2250;
      for (int i = cs + wv; i < ce; i += 4){
        float rr = sigmf(gload(GIAb + i) + gload(GHAb + i));
        float zz = sigmf(gload(GIAb + i + 750) + gload(GHAb + i + 750));
        float nn = tanhf(gload(GIAb + i + 1500) + rr*gload(GHAb + i + 1500));
        float h = (1.f - zz)*nn + zz*gload(ST + S_HASR + b*750 + i);
        float q = h*laqw + laqb;
        float sr[12]; float mx = -1e30f;
        #pragma unroll
        for (int m = 0; m < 12; m++){
          int j = lane + m*64;
          float s = (j < 750) ? q*kk[j] : -1e30f;
          sr[m] = s; mx = fmaxf(mx, s);
        }
        #pragma unroll
        for (int o = 32; o > 0; o >>= 1) mx = fmaxf(mx, __shfl_xor(mx, o));
        float se = 0.f, sv = 0.f;
        #pragma unroll
        for (int m = 0; m < 12; m++){
          int j = lane + m*64;
          if (j < 750){ float e = __expf(sr[m] - mx); se += e; sv += e*vv[j]; }
        }
        #pragma unroll
        for (int o = 32; o > 0; o >>= 1){ se += __shfl_xor(se, o); sv += __shfl_xor(sv, o); }
        if (lane == 0){
          gstore(ST + S_HASR + b*750 + i, h);
          gstore(anxt + b*750 + i, (sv/se)*laow + laob);
        }
      }
    } else if (blk < 164){
      gemv8(WD_H, 1152, 384, hdc, nullptr, 1, DBHH, ST + S_GHD, blk - 128, sm);
    }
    ep += 1; gridbar(flags, ep);

    // ---- Phase 2: ctx dots (ACTX/SCTX)  ||  GHA(t+1) gemv ----
    if (blk < 128){
      int b = blk >> 4, part = blk & 15;
      float* w_s = sm;
      for (int j = tid; j < 750; j += 256) w_s[j] = gload(anxt + b*750 + j);
      __syncthreads();
      int lane = tid & 63, wv = tid >> 6;
      for (int j = 0; j < 12; j++){
        int idx = part*48 + wv*12 + j;     // 0..767
        int which = (idx >= 384) ? 1 : 0;
        int d = idx - which*384;
        const unsigned short* M = (which == 0)
            ? EAT16 + ((size_t)b*384 + d)*750
            : EDT16 + ((size_t)b*384 + d)*750;
        float s = 0.f;
        #pragma unroll
        for (int m = 0; m < 11; m++){ int l = lane + m*64; s += bf2f(M[l])*w_s[l]; }
        { int l = lane + 704; if (l < 750) s += bf2f(M[l])*w_s[l]; }
        #pragma unroll
        for (int o = 32; o > 0; o >>= 1) s += __shfl_xor(s, o);
        if (lane == 0){
          if (which == 0) gstore(ST + S_ACTX + b*384 + d, s);
          else            gstore(ST + S_SCTX + b*384 + d, s);
        }
      }
      __syncthreads();
    } else if (blk < 199){
      gemv8(WA_H, 2250, 750, ST + S_HASR, nullptr, 1, ABHH, ST + S_GHA, blk - 128, sm);
    }
    ep += 1; gridbar(flags, ep);

    // ---- Phase 3: diar finale (8 blocks)  ||  GIA(t+1) gemv ----
    if (blk < 8){
      int b = blk;
      float* gid_s = sm;           // 1152
      float* hd_s  = sm + 1152;    // 384
      float* ha_s  = sm + 1536;    // 750
      float* ac_s  = sm + 2286;    // 384
      float* xs    = sm + 2670;    // 384 (SCTX)
      for (int j = tid; j < 750; j += 256) ha_s[j] = gload(ST + S_HASR + b*750 + j);
      for (int j = tid; j < 384; j += 256){
        ac_s[j] = gload(ST + S_ACTX + b*384 + j);
        xs[j]   = gload(ST + S_SCTX + b*384 + j);
      }
      __syncthreads();
      // GID = WD_IR @ sctx + GED(t)
      for (int r = tid; r < 1152; r += 256){
        const uint4* w4 = (const uint4*)(WD_IR + (size_t)r*384);
        float s = 0.f;
        #pragma unroll 4
        for (int kq = 0; kq < 48; kq++){
          uint4 w = w4[kq];
          const float* xp = xs + kq*8;
          s += bf2f((unsigned short)(w.x & 0xffff))*xp[0];
          s += bf2f((unsigned short)(w.x >> 16))   *xp[1];
          s += bf2f((unsigned short)(w.y & 0xffff))*xp[2];
          s += bf2f((unsigned short)(w.y >> 16))   *xp[3];
          s += bf2f((unsigned short)(w.z & 0xffff))*xp[4];
          s += bf2f((unsigned short)(w.z >> 16))   *xp[5];
          s += bf2f((unsigned short)(w.w & 0xffff))*xp[6];
          s += bf2f((unsigned short)(w.w >> 16))   *xp[7];
        }
        gid_s[r] = s + bf2f(GED16[(size_t)t*9216 + b*1152 + r]);
      }
      __syncthreads();
      float np = 0.f;
      for (int d = tid; d < 384; d += 256){
        int base = b*1152 + d;
        float rr = sigmf(gid_s[d]       + gload(ST + S_GHD + base));
        float zz = sigmf(gid_s[d + 384] + gload(ST + S_GHD + base + 384));
        float nn = tanhf(gid_s[d + 768] + rr*gload(ST + S_GHD + base + 768));
        float h = (1.f - zz)*nn + zz*gload(hdc + b*384 + d);
        hd_s[d] = h; gstore(hdn + b*384 + d, h); np += h*h;
      }
      red_s[tid] = np; __syncthreads();
      for (int k = 128; k > 0; k >>= 1){ if (tid < k) red_s[tid] += red_s[tid + k]; __syncthreads(); }
      float hn = sqrtf(red_s[0]);
      int sg = tid >> 5, si = tid & 31;
      float ps = 0.f;
      for (int j = si; j < 384; j += 32) ps += SPK[((size_t)(b*8 + sg))*384 + j]*hd_s[j];
      scp_s[tid] = ps; __syncthreads();
      if (tid < 8){
        float s = 0.f;
        for (int q = 0; q < 32; q++) s += scp_s[tid*32 + q];
        sc_s[tid] = s / (hn * ST[S_INVN + b*8 + tid]);
      }
      __syncthreads();
      if (tid == 0){
        float mx = -1e30f;
        for (int s2 = 0; s2 < 8; s2++) mx = fmaxf(mx, sc_s[s2]);
        float sum = 0.f;
        for (int s2 = 0; s2 < 8; s2++){ float e = __expf(sc_s[s2] - mx); beta_s[s2] = e; sum += e; }
        float inv = 1.f/sum;
        for (int s2 = 0; s2 < 8; s2++) beta_s[s2] *= inv;
        int td = TGTD[b*T_TXT + t];
        if (td != -100){ atomicAdd(&lacc[2], beta_s[td]); atomicAdd(&lacc[3], 1.f); }
      }
      __syncthreads();
      if (tid < 8) out[122880 + ((size_t)(b*T_TXT + t))*8 + tid] = beta_s[tid];
      if (tid < VOCAB){
        float lg = BIASC[tid];
        for (int d = 0; d < 384; d++) lg += ac_s[d]*bf2f(AO16[(size_t)d*VOCAB + tid]);
        for (int l = 0; l < 750; l++) lg += ha_s[l]*bf2f(W1T16[(size_t)l*VOCAB + tid]);
        #pragma unroll
        for (int s2 = 0; s2 < 8; s2++) lg += beta_s[s2]*SPKV[(size_t)(b*8 + s2)*VOCAB + tid];
        out[((size_t)(b*T_TXT + t))*VOCAB + tid] = lg;
        int ta = TGTA[b*T_TXT + t];
        if (ta == tid) atomicAdd(&lacc[0], lg);
        if (tid == 0 && ta != -100) atomicAdd(&lacc[1], 1.f);
      }
      __syncthreads();
    } else if (blk < 79 && t + 1 < T_TXT){
      gemv8(WA_I, 2250, 384, ST + S_ACTX, GEA16 + (size_t)(t+1)*18000, 0, nullptr,
            ST + S_GIA, blk - 8, sm);
    }
    ep += 1; gridbar(flags, ep);
  }

  if (blk == 0 && tid == 0){
    float la = gload(lacc + 0)/fmaxf(gload(lacc + 1), 1.f);
    float ld = gload(lacc + 2)/fmaxf(gload(lacc + 3), 1.f);
    out[139264] = -(la + ld);
  }
}

// ---------------------------------------------------------------------------
extern "C" void kernel_launch(void* const* d_in, const int* in_sizes, int n_in,
                              void* d_out, int out_size, void* d_ws, size_t ws_size,
                              hipStream_t stream)
{
  (void)in_sizes; (void)n_in; (void)out_size; (void)ws_size;
  float* ws  = (float*)d_ws;
  float* out = (float*)d_out;

  const float* IN0   = (const float*)d_in[0];
  const float* SPK   = (const float*)d_in[1];
  const float* C1W   = (const float*)d_in[2];
  const float* C1B   = (const float*)d_in[3];
  const float* C2W   = (const float*)d_in[4];
  const float* C2B   = (const float*)d_in[5];
  const float* LAQ   = (const float*)d_in[30];
  const float* LAK   = (const float*)d_in[31];
  const float* LAV   = (const float*)d_in[32];
  const float* LAIB  = (const float*)d_in[33];
  const float* LAOW  = (const float*)d_in[34];
  const float* LAOB  = (const float*)d_in[35];
  const float* EMB   = (const float*)d_in[36];
  const float* AWIH  = (const float*)d_in[37];
  const float* AWHH  = (const float*)d_in[38];
  const float* ABIH  = (const float*)d_in[39];
  const float* ABHH  = (const float*)d_in[40];
  const float* DWIH  = (const float*)d_in[41];
  const float* DWHH  = (const float*)d_in[42];
  const float* DBIH  = (const float*)d_in[43];
  const float* DBHH  = (const float*)d_in[44];
  const float* AOW   = (const float*)d_in[45];
  const float* AOB   = (const float*)d_in[46];
  const float* D2AW  = (const float*)d_in[47];
  const float* D2AB  = (const float*)d_in[48];
  const float* H2AW  = (const float*)d_in[49];
  const float* H2AB  = (const float*)d_in[50];
  const int*   TGTA  = (const int*)d_in[51];
  const int*   TGTD  = (const int*)d_in[52];

  // ---- workspace layout (float offsets) ----
  const size_t O_X   = 0;
  const size_t O_EA  = 2304000;
  const size_t O_ED  = 4608000;
  const size_t O_ST  = 6912000;   // ST_SIZE floats of state (zeroed each call)
  const size_t O_SCR = 7014200;
  // encoder scratch
  const size_t S_QKV = O_SCR;
  const size_t S_KT  = O_SCR + 6912000;
  const size_t S_CTX = O_SCR + 9216000;
  const size_t S_Y   = O_SCR + 11520000;
  const size_t S_H   = O_SCR + 13824000;
  const size_t X1T   = S_KT;
  const size_t P1    = S_H;
  const size_t P2    = S_QKV;
  // decode precompute overlay (written after encoder finishes)
  const size_t WIHAT_A16 = O_SCR + 0;        // 384x2250 bf16
  const size_t WHHT_A16  = O_SCR + 432000;   // 750x2250 bf16
  const size_t WHHT_D16  = O_SCR + 1496934;  // 384x1152 bf16
  const size_t EAT16o    = O_SCR + 1718118;  // 8x384x750 bf16
  const size_t EDT16o    = O_SCR + 2870118;  // 8x384x750 bf16
  const size_t AO16o     = O_SCR + 4022118;  // 384x60 bf16
  const size_t W1T16o    = O_SCR + 4033638;  // 750x60 bf16
  const size_t SPKVo     = O_SCR + 4056138;  // 64x60 fp32
  const size_t BIASCo    = O_SCR + 4059978;  // 60 fp32
  const size_t H2AWTo    = O_SCR + 4060038;  // 750x384 fp32
  const size_t D2ATfo    = O_SCR + 4348038;  // 384x384 fp32
  const size_t W1fo      = O_SCR + 4495494;  // 60x750 fp32
  const size_t W2fo      = O_SCR + 4540494;  // 60x384 fp32
  const size_t EMBTo     = O_SCR + 4563534;  // 2048x384 fp32
  const size_t GEA16o    = O_SCR + 5349966;  // 2048x2250 bf16
  const size_t GED16o    = O_SCR + 7653966;  // 2048x1152 bf16
  const size_t WDIR16o   = O_SCR + 8833614;  // 1152x384 bf16 row-major

  // 1) zero decode state + loss accumulators + barrier flags
  hipMemsetAsync((void*)(ws + O_ST), 0, ST_SIZE*sizeof(float), stream);

  // 2) convs via im2col + GEMM
  im2col1<<<dim3(1500,8), 256, 0, stream>>>(IN0, ws + P1);
  gemm_k<1,0><<<dim3(6,94), 256, 0, stream>>>(ws+P1, 240, C1W, 240, C1B, nullptr, ws+X1T, 384, 12000, 384, 240);
  im2col2<<<dim3(750,8), 384, 0, stream>>>(ws+X1T, ws+P2);
  gemm_k<1,0><<<dim3(6,47), 256, 0, stream>>>(ws+P2, 1152, C2W, 1152, C2B, nullptr, ws+O_X, 384, 6000, 384, 1152);

  hipMemcpyAsync(ws+O_EA, ws+O_X, 2304000*sizeof(float), hipMemcpyDeviceToDevice, stream);
  hipMemcpyAsync(ws+O_ED, ws+O_X, 2304000*sizeof(float), hipMemcpyDeviceToDevice, stream);

  // 3) encoder stacks
  auto enc_layer = [&](float* Xb, const float* qw, const float* qb, const float* ow,
                       const float* ob, const float* f1w, const float* f1b,
                       const float* f2w, const float* f2b,
                       const float* g1, const float* b1, const float* g2, const float* b2){
    gemm_k<0,0><<<dim3(18,47), 256, 0, stream>>>(Xb, 384, qw, 384, qb, nullptr, ws+S_QKV, 1152, 6000, 1152, 384);
    kt_k<<<dim3(3,24,32), dim3(32,8), 0, stream>>>(ws+S_QKV, ws+S_KT);
    attn_enc<<<dim3(47,4,8), 1024, 0, stream>>>(ws+S_QKV, ws+S_KT, ws+S_CTX);
    gemm_k<0,1><<<dim3(6,47), 256, 0, stream>>>(ws+S_CTX, 384, ow, 384, ob, Xb, ws+S_Y, 384, 6000, 384, 384);
    ln_k<<<6000, 128, 0, stream>>>(ws+S_Y, g1, b1);
    gemm_k<1,0><<<dim3(16,47), 256, 0, stream>>>(ws+S_Y, 384, f1w, 384, f1b, nullptr, ws+S_H, 1024, 6000, 1024, 384);
    gemm_k<0,1><<<dim3(6,47), 256, 0, stream>>>(ws+S_H, 1024, f2w, 1024, f2b, ws+S_Y, Xb, 384, 6000, 384, 1024);
    ln_k<<<6000, 128, 0, stream>>>(Xb, g2, b2);
  };
  for (int st = 0; st < 2; st++){
    int base = (st == 0) ? 6 : 18;
    float* Xb = ws + ((st == 0) ? O_EA : O_ED);
    const float* qkvw = (const float*)d_in[base+0];
    const float* qkvb = (const float*)d_in[base+1];
    const float* aow  = (const float*)d_in[base+2];
    const float* aob2 = (const float*)d_in[base+3];
    const float* f1w  = (const float*)d_in[base+4];
    const float* f1b  = (const float*)d_in[base+5];
    const float* f2w  = (const float*)d_in[base+6];
    const float* f2b  = (const float*)d_in[base+7];
    const float* g1   = (const float*)d_in[base+8];
    const float* b1   = (const float*)d_in[base+9];
    const float* g2   = (const float*)d_in[base+10];
    const float* b2   = (const float*)d_in[base+11];
    for (int l = 0; l < 2; l++){
      enc_layer(Xb, qkvw + (size_t)l*1152*384, qkvb + (size_t)l*1152,
                aow + (size_t)l*384*384, aob2 + (size_t)l*384,
                f1w + (size_t)l*1024*384, f1b + (size_t)l*1024,
                f2w + (size_t)l*384*1024, f2b + (size_t)l*384,
                g1 + (size_t)l*384, b1 + (size_t)l*384, g2 + (size_t)l*384, b2 + (size_t)l*384);
    }
  }

  // 4) decode precompute
  transpose_bf16_k<<<dim3(12,71), dim3(32,8), 0, stream>>>(AWIH, 768, 2250, 384, (unsigned short*)(ws+WIHAT_A16), 0, 0);
  transpose_bf16_k<<<dim3(24,71), dim3(32,8), 0, stream>>>(AWHH, 750, 2250, 750, (unsigned short*)(ws+WHHT_A16), 0, 0);
  transpose_bf16_k<<<dim3(12,36), dim3(32,8), 0, stream>>>(DWHH, 384, 1152, 384, (unsigned short*)(ws+WHHT_D16), 0, 0);
  convrow_k<<<1152, 384, 0, stream>>>(DWIH, 768, 384, (unsigned short*)(ws+WDIR16o));
  transpose_bf16_k<<<dim3(12,24,8), dim3(32,8), 0, stream>>>(ws+O_EA, 384, 750, 384, (unsigned short*)(ws+EAT16o), 288000, 288000);
  transpose_bf16_k<<<dim3(12,24,8), dim3(32,8), 0, stream>>>(ws+O_ED, 384, 750, 384, (unsigned short*)(ws+EDT16o), 288000, 288000);
  transpose_bf16_k<<<dim3(12,2),  dim3(32,8), 0, stream>>>(AOW, 384, 60, 384, (unsigned short*)(ws+AO16o), 0, 0);
  transpose_k<<<dim3(24,12), dim3(32,8), 0, stream>>>(H2AW, 750, 384, 750, ws+H2AWTo);
  transpose_k<<<dim3(12,12), dim3(32,8), 0, stream>>>(D2AW, 384, 384, 384, ws+D2ATfo);
  gemm_k<0,0,0,1><<<dim3(12,1), 256, 0, stream>>>(AOW, 384, ws+H2AWTo, 384, nullptr, nullptr, ws+W1fo, 750, 60, 750, 384);
  transpose_bf16_k<<<dim3(24,2), dim3(32,8), 0, stream>>>(ws+W1fo, 750, 60, 750, (unsigned short*)(ws+W1T16o), 0, 0);
  gemm_k<0,0,0,1><<<dim3(6,1), 256, 0, stream>>>(AOW, 384, ws+D2ATfo, 384, nullptr, nullptr, ws+W2fo, 384, 60, 384, 384);
  gemm_k<0,0,0,1><<<dim3(1,1), 256, 0, stream>>>(SPK, 384, ws+W2fo, 384, nullptr, nullptr, ws+SPKVo, 60, 64, 60, 384);
  biasc_k<<<1, 64, 0, stream>>>(AOB, H2AB, D2AB, AOW, ws+BIASCo);
  embed_k<<<2048, 384, 0, stream>>>(EMB, TGTA, ws+EMBTo);
  gemm_k<0,0,1><<<dim3(36,16), 256, 0, stream>>>(ws+EMBTo, 384, AWIH+384, 768, ABIH, nullptr, (float*)(ws+GEA16o), 2250, 2048, 2250, 384);
  gemm_k<0,0,1><<<dim3(18,16), 256, 0, stream>>>(ws+EMBTo, 384, DWIH+384, 768, DBIH, nullptr, (float*)(ws+GED16o), 1152, 2048, 1152, 384);
  vla_k<<<1500, 256, 0, stream>>>(ws+O_EA, LAV, LAIB, ws+O_ST+S_VLA);
  invn_k<<<64, 64, 0, stream>>>(SPK, ws+O_ST+S_INVN);

  // 5) the whole decode loop: one persistent launch
  decode_persist<<<256, 256, 0, stream>>>(
      (const unsigned short*)(ws+WIHAT_A16), (const unsigned short*)(ws+WHHT_A16),
      (const unsigned short*)(ws+WDIR16o), (const unsigned short*)(ws+WHHT_D16),
      (const unsigned short*)(ws+EAT16o), (const unsigned short*)(ws+EDT16o),
      (const unsigned short*)(ws+AO16o), (const unsigned short*)(ws+W1T16o),
      (const unsigned short*)(ws+GEA16o), (const unsigned short*)(ws+GED16o),
      ws+SPKVo, ws+BIASCo, ABHH, DBHH,
      LAQ, LAK, LAIB, LAOW, LAOB,
      SPK, TGTA, TGTD,
      ws + O_ST, out, (unsigned*)(ws + O_ST + S_FLG));
}

// Round 6
// 40181.000 us; speedup vs baseline: 1.1539x; 1.1539x over previous
//
#include <hip/hip_runtime.h>
#include <math.h>

// ---------------------------------------------------------------------------
// Model constants
#define L_ENC 750
#define T_AUD 1500
#define DD    384
#define FF    1024
#define NHH   4
#define HDIM  96
#define VOCAB 60
#define T_TXT 256
#define BB    8

// ---- state offsets (floats, relative to ST = ws + O_ST) ----
#define S_HASR 0
#define S_ATT0 6000
#define S_ATT1 12000
#define S_HD0  18000
#define S_HD1  21072
#define S_ACTX 24144
#define S_SCTX 27216
#define S_GIA  33360
#define S_GHA  51360
#define S_GHD  78576
#define S_LACC 87792
#define S_VLA  87800
#define S_INVN 93800
#define ST_SIZE 94000

static __device__ __forceinline__ float sigmf(float x){ return 1.f/(1.f + __expf(-x)); }

static __device__ __forceinline__ float bf2f(unsigned short u){
  union { unsigned u; float f; } c; c.u = ((unsigned)u) << 16; return c.f;
}
static __device__ __forceinline__ unsigned short f2bf(float f){
  unsigned u = __float_as_uint(f);
  unsigned r = (u + 0x7FFFu + ((u >> 16) & 1u)) >> 16;
  return (unsigned short)r;
}

// ---------------------------------------------------------------------------
// Generic tiled transpose: out[c*R + r] = in[r*ldin + c]
__global__ void transpose_k(const float* __restrict__ in, int ldin, int R, int C,
                            float* __restrict__ out){
  __shared__ float t[32][33];
  int c0 = blockIdx.x*32, r0 = blockIdx.y*32;
  int x = threadIdx.x, y = threadIdx.y;
  for (int i = y; i < 32; i += 8){
    int r = r0 + i, c = c0 + x;
    t[i][x] = (r < R && c < C) ? in[(size_t)r*ldin + c] : 0.f;
  }
  __syncthreads();
  for (int i = y; i < 32; i += 8){
    int c = c0 + i, r = r0 + x;
    if (c < C && r < R) out[(size_t)c*R + r] = t[x][i];
  }
}

// Transpose + convert to bf16, optionally batched over blockIdx.z
__global__ void transpose_bf16_k(const float* __restrict__ in, int ldin, int R, int C,
                                 unsigned short* __restrict__ out,
                                 size_t inBatch, size_t outBatch){
  __shared__ float t[32][33];
  int z = blockIdx.z;
  in  += (size_t)z*inBatch;
  out += (size_t)z*outBatch;
  int c0 = blockIdx.x*32, r0 = blockIdx.y*32;
  int x = threadIdx.x, y = threadIdx.y;
  for (int i = y; i < 32; i += 8){
    int r = r0 + i, c = c0 + x;
    t[i][x] = (r < R && c < C) ? in[(size_t)r*ldin + c] : 0.f;
  }
  __syncthreads();
  for (int i = y; i < 32; i += 8){
    int c = c0 + i, r = r0 + x;
    if (c < C && r < R) out[(size_t)c*R + r] = f2bf(t[x][i]);
  }
}

// Row-major fp32 -> bf16 copy of a column slice: out[r*C+c] = in[r*ldin+c]
__global__ __launch_bounds__(384) void convrow_k(const float* __restrict__ in, int ldin, int C,
                                                 unsigned short* __restrict__ out){
  int r = blockIdx.x, c = threadIdx.x;
  if (c < C) out[(size_t)r*C + c] = f2bf(in[(size_t)r*ldin + c]);
}

// K-transpose for encoder attention
__global__ void kt_k(const float* __restrict__ QKV, float* __restrict__ KT){
  __shared__ float t[32][33];
  int z = blockIdx.z; int b = z >> 2, h = z & 3;
  const float* in = QKV + (size_t)b*L_ENC*1152 + 384 + h*HDIM;
  float* out = KT + (size_t)z*HDIM*L_ENC;
  int c0 = blockIdx.x*32, r0 = blockIdx.y*32;
  int x = threadIdx.x, y = threadIdx.y;
  for (int i = y; i < 32; i += 8){
    int r = r0 + i, c = c0 + x;
    t[i][x] = (r < L_ENC && c < HDIM) ? in[(size_t)r*1152 + c] : 0.f;
  }
  __syncthreads();
  for (int i = y; i < 32; i += 8){
    int c = c0 + i, r = r0 + x;
    if (c < HDIM && r < L_ENC) out[(size_t)c*L_ENC + r] = t[x][i];
  }
}

// ---------------------------------------------------------------------------
// Generic fp32 GEMM: C[M,N] = act(A[M,K] @ W[N,K]^T + bias[N] (+ Res[M,N]))
template<int RELU, int HASRES, int BF16OUT = 0, int NOBIAS = 0>
__global__ __launch_bounds__(256) void gemm_k(
    const float* __restrict__ A, int lda, const float* __restrict__ W, int ldw,
    const float* __restrict__ bias, const float* __restrict__ Res,
    float* __restrict__ C, int ldc, int M, int N, int K)
{
  __shared__ __align__(16) float As[16][132];
  __shared__ __align__(16) float Ws[16][68];
  int tid = threadIdx.x;
  int row0 = blockIdx.y*128, col0 = blockIdx.x*64;
  int tx = tid & 15, ty = tid >> 4;
  int lr = tid >> 2, lk = (tid & 3)*4;
  float acc[8][4] = {};
  for (int k0 = 0; k0 < K; k0 += 16){
    float4 a0 = make_float4(0,0,0,0), a1 = make_float4(0,0,0,0), w0 = make_float4(0,0,0,0);
    int r0i = row0 + lr, r1i = row0 + 64 + lr, wri = col0 + lr;
    if (r0i < M) a0 = *(const float4*)(A + (size_t)r0i*lda + k0 + lk);
    if (r1i < M) a1 = *(const float4*)(A + (size_t)r1i*lda + k0 + lk);
    if (wri < N) w0 = *(const float4*)(W + (size_t)wri*ldw + k0 + lk);
    As[lk+0][lr] = a0.x; As[lk+1][lr] = a0.y; As[lk+2][lr] = a0.z; As[lk+3][lr] = a0.w;
    As[lk+0][64+lr] = a1.x; As[lk+1][64+lr] = a1.y; As[lk+2][64+lr] = a1.z; As[lk+3][64+lr] = a1.w;
    Ws[lk+0][lr] = w0.x; Ws[lk+1][lr] = w0.y; Ws[lk+2][lr] = w0.z; Ws[lk+3][lr] = w0.w;
    __syncthreads();
    #pragma unroll
    for (int k = 0; k < 16; k++){
      float4 b4 = *(const float4*)&Ws[k][tx*4];
      float4 a4 = *(const float4*)&As[k][ty*8];
      float4 a5 = *(const float4*)&As[k][ty*8+4];
      acc[0][0] += a4.x*b4.x; acc[0][1] += a4.x*b4.y; acc[0][2] += a4.x*b4.z; acc[0][3] += a4.x*b4.w;
      acc[1][0] += a4.y*b4.x; acc[1][1] += a4.y*b4.y; acc[1][2] += a4.y*b4.z; acc[1][3] += a4.y*b4.w;
      acc[2][0] += a4.z*b4.x; acc[2][1] += a4.z*b4.y; acc[2][2] += a4.z*b4.z; acc[2][3] += a4.z*b4.w;
      acc[3][0] += a4.w*b4.x; acc[3][1] += a4.w*b4.y; acc[3][2] += a4.w*b4.z; acc[3][3] += a4.w*b4.w;
      acc[4][0] += a5.x*b4.x; acc[4][1] += a5.x*b4.y; acc[4][2] += a5.x*b4.z; acc[4][3] += a5.x*b4.w;
      acc[5][0] += a5.y*b4.x; acc[5][1] += a5.y*b4.y; acc[5][2] += a5.y*b4.z; acc[5][3] += a5.y*b4.w;
      acc[6][0] += a5.z*b4.x; acc[6][1] += a5.z*b4.y; acc[6][2] += a5.z*b4.z; acc[6][3] += a5.z*b4.w;
      acc[7][0] += a5.w*b4.x; acc[7][1] += a5.w*b4.y; acc[7][2] += a5.w*b4.z; acc[7][3] += a5.w*b4.w;
    }
    __syncthreads();
  }
  #pragma unroll
  for (int ii = 0; ii < 8; ii++){
    int m = row0 + ty*8 + ii;
    if (m >= M) continue;
    #pragma unroll
    for (int jj = 0; jj < 4; jj++){
      int n = col0 + tx*4 + jj;
      if (n >= N) continue;
      float v = acc[ii][jj];
      if (!NOBIAS) v += bias[n];
      if (HASRES) v += Res[(size_t)m*ldc + n];
      if (RELU) v = fmaxf(v, 0.f);
      if (BF16OUT) ((unsigned short*)C)[(size_t)m*ldc + n] = f2bf(v);
      else C[(size_t)m*ldc + n] = v;
    }
  }
}

// ---------------------------------------------------------------------------
// im2col for conv1 (k=3, pad=1, stride=1)
__global__ void im2col1(const float* __restrict__ in, float* __restrict__ P){
  int t = blockIdx.x, b = blockIdx.y, i = threadIdx.x;
  if (i >= 240) return;
  int ic = i/3, kt = i - ic*3;
  int p = t + kt - 1;
  P[((size_t)(b*T_AUD + t))*240 + i] = (p >= 0 && p < T_AUD) ? in[((size_t)(b*80 + ic))*T_AUD + p] : 0.f;
}

// im2col for conv2 (k=3, pad=1, stride=2)
__global__ __launch_bounds__(384) void im2col2(const float* __restrict__ X1T, float* __restrict__ P){
  int t = blockIdx.x, b = blockIdx.y, ic = threadIdx.x;
  size_t ob = ((size_t)(b*L_ENC + t))*1152 + (size_t)ic*3;
  #pragma unroll
  for (int kt = 0; kt < 3; kt++){
    int p = 2*t + kt - 1;
    P[ob + kt] = (p >= 0 && p < T_AUD) ? X1T[((size_t)(b*T_AUD + p))*DD + ic] : 0.f;
  }
}

// ---------------------------------------------------------------------------
// LayerNorm in-place over rows of 384
__global__ __launch_bounds__(128) void ln_k(float* __restrict__ X, const float* __restrict__ g,
                                            const float* __restrict__ bt){
  int r = blockIdx.x, tid = threadIdx.x;
  float* p = X + (size_t)r*DD;
  float v0 = p[tid], v1 = p[tid+128], v2 = p[tid+256];
  __shared__ float red[128];
  red[tid] = v0+v1+v2; __syncthreads();
  for (int k = 64; k > 0; k >>= 1){ if (tid < k) red[tid] += red[tid+k]; __syncthreads(); }
  float m = red[0] * (1.f/384.f);
  __syncthreads();
  float d0 = v0-m, d1 = v1-m, d2 = v2-m;
  red[tid] = d0*d0 + d1*d1 + d2*d2; __syncthreads();
  for (int k = 64; k > 0; k >>= 1){ if (tid < k) red[tid] += red[tid+k]; __syncthreads(); }
  float rs = rsqrtf(red[0]*(1.f/384.f) + 1e-5f);
  p[tid]     = d0*rs*g[tid]     + bt[tid];
  p[tid+128] = d1*rs*g[tid+128] + bt[tid+128];
  p[tid+256] = d2*rs*g[tid+256] + bt[tid+256];
}

// ---------------------------------------------------------------------------
// Encoder attention, fused scores+softmax+AV.
__global__ __launch_bounds__(1024) void attn_enc(const float* __restrict__ QKV,
    const float* __restrict__ KT, float* __restrict__ ctx){
  int b = blockIdx.z, h = blockIdx.y, i0 = blockIdx.x*16;
  int tid = threadIdx.x, lane = tid & 63, wv = tid >> 6;
  __shared__ float q_s[16][96];
  __shared__ float p_s[16][752];
  __shared__ float den_s[16];
  for (int idx = tid; idx < 16*96; idx += 1024){
    int r2 = idx/96, c = idx - r2*96; int i = i0 + r2;
    q_s[r2][c] = (i < L_ENC) ? QKV[((size_t)(b*L_ENC + i))*1152 + h*HDIM + c]*0.10206207f : 0.f;
  }
  __syncthreads();
  int i = i0 + wv;
  const float* ktb = KT + ((size_t)(b*4 + h))*HDIM*L_ENC;
  if (i < L_ENC){
    float sr[12] = {0,0,0,0,0,0,0,0,0,0,0,0};
    for (int c = 0; c < 96; c++){
      float qc = q_s[wv][c];
      const float* kr = ktb + c*L_ENC + lane;
      #pragma unroll
      for (int jt = 0; jt < 12; jt++) sr[jt] += qc*kr[jt*64];
    }
    float mx = -1e30f;
    #pragma unroll
    for (int jt = 0; jt < 12; jt++){ if (lane + jt*64 < L_ENC) mx = fmaxf(mx, sr[jt]); }
    #pragma unroll
    for (int o = 32; o > 0; o >>= 1) mx = fmaxf(mx, __shfl_xor(mx, o));
    float den = 0.f;
    #pragma unroll
    for (int jt = 0; jt < 12; jt++){
      int j = lane + jt*64;
      if (j < L_ENC){ float e = __expf(sr[jt]-mx); p_s[wv][j] = e; den += e; }
    }
    #pragma unroll
    for (int o = 32; o > 0; o >>= 1) den += __shfl_xor(den, o);
    if (lane == 0) den_s[wv] = den;
  }
  __syncthreads();
  if (i < L_ENC){
    float idn = 1.f/den_s[wv];
    const float* vb = QKV + (size_t)b*L_ENC*1152 + 768 + h*HDIM;
    float a0 = 0.f, a1 = 0.f;
    for (int j = 0; j < L_ENC; j++){
      float pj = p_s[wv][j];
      const float* vr = vb + (size_t)j*1152;
      a0 += pj*vr[lane];
      if (lane < 32) a1 += pj*vr[lane + 64];
    }
    size_t ob = ((size_t)(b*L_ENC + i))*DD + h*HDIM;
    ctx[ob + lane] = a0*idn;
    if (lane < 32) ctx[ob + lane + 64] = a1*idn;
  }
}

// ---------------------------------------------------------------------------
// Decode precompute helpers
__global__ __launch_bounds__(384) void embed_k(const float* __restrict__ emb,
    const int* __restrict__ tgtA, float* __restrict__ E){
  int row = blockIdx.x; int t = row >> 3, b = row & 7;
  int tok = 0;
  if (t > 0){ int v = tgtA[b*T_TXT + t - 1]; tok = (v == -100) ? 0 : v; }
  E[(size_t)row*DD + threadIdx.x] = emb[(size_t)tok*DD + threadIdx.x];
}

__global__ __launch_bounds__(256) void vla_k(const float* __restrict__ EA,
    const float* __restrict__ lav, const float* __restrict__ lain, float* __restrict__ VLA){
  int row = blockIdx.x*4 + (threadIdx.x >> 6);
  int lane = threadIdx.x & 63;
  if (row >= BB*L_ENC) return;
  const float* p = EA + (size_t)row*DD;
  float s = 0.f;
  for (int d = lane; d < DD; d += 64) s += p[d]*lav[d];
  #pragma unroll
  for (int o = 32; o > 0; o >>= 1) s += __shfl_xor(s, o);
  if (lane == 0) VLA[row] = s + lain[2];
}

__global__ void invn_k(const float* __restrict__ inv, float* __restrict__ INVN){
  int row = blockIdx.x; int lane = threadIdx.x;
  float s = 0.f;
  for (int d = lane; d < DD; d += 64){ float v = inv[(size_t)row*DD + d]; s += v*v; }
  #pragma unroll
  for (int o = 32; o > 0; o >>= 1) s += __shfl_xor(s, o);
  if (lane == 0) INVN[row] = sqrtf(s);
}

// biasC[v] = AOB[v] + sum_d (H2AB[d]+D2AB[d])*AOW[v][d]
__global__ void biasc_k(const float* __restrict__ AOB, const float* __restrict__ H2AB,
                        const float* __restrict__ D2AB, const float* __restrict__ AOW,
                        float* __restrict__ biasC){
  int v = threadIdx.x; if (v >= VOCAB) return;
  float s = AOB[v];
  for (int d = 0; d < DD; d++) s += (H2AB[d] + D2AB[d])*AOW[(size_t)v*DD + d];
  biasC[v] = s;
}

// init GIA(0)=GEA(0), GHA(0)=ABHH
__global__ __launch_bounds__(256) void init_gates_k(const unsigned short* __restrict__ GEA16,
    const float* __restrict__ ABHH, float* __restrict__ ST){
  int idx = blockIdx.x*256 + threadIdx.x;
  if (idx < 18000){
    ST[S_GIA + idx] = bf2f(GEA16[idx]);
    ST[S_GHA + idx] = ABHH[idx % 2250];
  }
}

// ---------------------------------------------------------------------------
// GEMV for 8 batches: out[b][r] = sum_k bf16 W[k][r] * x[b][k] + extra
// emode 0: extra16[b*NR + r] (bf16), emode 1: bias[r] (fp32)
__device__ __forceinline__ void gemv8(const unsigned short* __restrict__ W, int NR, int K,
    const float* __restrict__ x, const unsigned short* __restrict__ extra16, int emode,
    const float* __restrict__ bias, float* __restrict__ out, int vb, float* sm)
{
  int tid = threadIdx.x;
  float* xs = sm;
  float* pg = sm + K*8;
  for (int idx = tid; idx < 8*K; idx += 256){
    int b = idx / K, k = idx - b*K;
    xs[k*8 + b] = x[idx];
  }
  __syncthreads();
  int rl = tid & 31, kp = tid >> 5;
  int r = vb*32 + rl;
  float a0=0,a1=0,a2=0,a3=0,a4=0,a5=0,a6=0,a7=0;
  if (r < NR){
    int kc = (K + 7) >> 3;
    int k0 = kp*kc, k1 = k0 + kc; if (k1 > K) k1 = K;
    const unsigned short* Wp = W + (size_t)k0*NR + r;
    for (int k = k0; k < k1; k++){
      float w = bf2f(*Wp); Wp += NR;
      const float4 v0 = *(const float4*)&xs[k*8];
      const float4 v1 = *(const float4*)&xs[k*8+4];
      a0 += w*v0.x; a1 += w*v0.y; a2 += w*v0.z; a3 += w*v0.w;
      a4 += w*v1.x; a5 += w*v1.y; a6 += w*v1.z; a7 += w*v1.w;
    }
  }
  float* pr = pg + (size_t)(kp*32 + rl)*8;
  pr[0]=a0; pr[1]=a1; pr[2]=a2; pr[3]=a3; pr[4]=a4; pr[5]=a5; pr[6]=a6; pr[7]=a7;
  __syncthreads();
  int b = tid >> 5, rr = tid & 31;
  int r2 = vb*32 + rr;
  if (r2 < NR){
    float s = 0.f;
    #pragma unroll
    for (int q = 0; q < 8; q++) s += pg[(size_t)(q*32 + rr)*8 + b];
    if (emode == 0) s += bf2f(extra16[(size_t)b*NR + r2]);
    else s += bias[r2];
    out[(size_t)b*NR + r2] = s;
  }
}

// ---------------------------------------------------------------------------
// Decode phase 1 (164 blocks): h_asr GRU + rank-1 attention row || GHD(t) gemv
__global__ __launch_bounds__(256) void ph1_k(
    float* __restrict__ ST, const float* __restrict__ acur, float* __restrict__ anxt,
    const float* __restrict__ hdc, const unsigned short* __restrict__ WD_H,
    const float* __restrict__ DBHH,
    const float* __restrict__ LAQ, const float* __restrict__ LAK,
    const float* __restrict__ LAIB, const float* __restrict__ LAOW,
    const float* __restrict__ LAOB)
{
  __shared__ float sm[8064];
  int blk = blockIdx.x, tid = threadIdx.x;
  if (blk < 128){
    float laqw = LAQ[0], laqb = LAIB[0], lakw = LAK[0], lakb = LAIB[1];
    float laow = LAOW[0], laob = LAOB[0];
    int b = blk >> 4, ch = blk & 15;
    int cs = ch*47, ce = cs + 47; if (ce > 750) ce = 750;
    float* kk = sm; float* vv = sm + 752;
    for (int j = tid; j < 750; j += 256){
      kk[j] = acur[b*750 + j]*lakw + lakb;
      vv[j] = ST[S_VLA + b*750 + j];
    }
    __syncthreads();
    int lane = tid & 63, wv = tid >> 6;
    const float* GIAb = ST + S_GIA + b*2250;
    const float* GHAb = ST + S_GHA + b*2250;
    for (int i = cs + wv; i < ce; i += 4){
      float rr = sigmf(GIAb[i] + GHAb[i]);
      float zz = sigmf(GIAb[i+750] + GHAb[i+750]);
      float nn = tanhf(GIAb[i+1500] + rr*GHAb[i+1500]);
      float h = (1.f - zz)*nn + zz*ST[S_HASR + b*750 + i];
      float q = h*laqw + laqb;
      float sr[12]; float mx = -1e30f;
      #pragma unroll
      for (int m = 0; m < 12; m++){
        int j = lane + m*64;
        float s = (j < 750) ? q*kk[j] : -1e30f;
        sr[m] = s; mx = fmaxf(mx, s);
      }
      #pragma unroll
      for (int o = 32; o > 0; o >>= 1) mx = fmaxf(mx, __shfl_xor(mx, o));
      float se = 0.f, sv = 0.f;
      #pragma unroll
      for (int m = 0; m < 12; m++){
        int j = lane + m*64;
        if (j < 750){ float e = __expf(sr[m] - mx); se += e; sv += e*vv[j]; }
      }
      #pragma unroll
      for (int o = 32; o > 0; o >>= 1){ se += __shfl_xor(se, o); sv += __shfl_xor(sv, o); }
      if (lane == 0){
        ST[S_HASR + b*750 + i] = h;
        anxt[b*750 + i] = (sv/se)*laow + laob;
      }
    }
  } else {
    gemv8(WD_H, 1152, 384, hdc, nullptr, 1, DBHH, ST + S_GHD, blk - 128, sm);
  }
}

// ---------------------------------------------------------------------------
// Decode phase 2 (199 blocks): ctx dots (ACTX/SCTX) || GHA(t+1) gemv
__global__ __launch_bounds__(256) void ph2_k(
    float* __restrict__ ST, const float* __restrict__ anxt,
    const unsigned short* __restrict__ EAT16, const unsigned short* __restrict__ EDT16,
    const unsigned short* __restrict__ WA_H, const float* __restrict__ ABHH)
{
  __shared__ float sm[8064];
  int blk = blockIdx.x, tid = threadIdx.x;
  if (blk < 128){
    int b = blk >> 4, part = blk & 15;
    float* w_s = sm;
    for (int j = tid; j < 750; j += 256) w_s[j] = anxt[b*750 + j];
    __syncthreads();
    int lane = tid & 63, wv = tid >> 6;
    for (int j = 0; j < 12; j++){
      int idx = part*48 + wv*12 + j;     // 0..767
      int which = (idx >= 384) ? 1 : 0;
      int d = idx - which*384;
      const unsigned short* M = (which == 0)
          ? EAT16 + ((size_t)b*384 + d)*750
          : EDT16 + ((size_t)b*384 + d)*750;
      float s = 0.f;
      #pragma unroll
      for (int m = 0; m < 11; m++){ int l = lane + m*64; s += bf2f(M[l])*w_s[l]; }
      { int l = lane + 704; if (l < 750) s += bf2f(M[l])*w_s[l]; }
      #pragma unroll
      for (int o = 32; o > 0; o >>= 1) s += __shfl_xor(s, o);
      if (lane == 0){
        if (which == 0) ST[S_ACTX + b*384 + d] = s;
        else            ST[S_SCTX + b*384 + d] = s;
      }
    }
  } else {
    gemv8(WA_H, 2250, 750, ST + S_HASR, nullptr, 1, ABHH, ST + S_GHA, blk - 128, sm);
  }
}

// ---------------------------------------------------------------------------
// Decode phase 3 (79 blocks): diar finale (8) || GIA(t+1) gemv (71)
__global__ __launch_bounds__(256) void ph3_k(
    float* __restrict__ ST, const float* __restrict__ hdc, float* __restrict__ hdn,
    const unsigned short* __restrict__ WD_IR, const unsigned short* __restrict__ GED16,
    const unsigned short* __restrict__ WA_I, const unsigned short* __restrict__ GEA16,
    const unsigned short* __restrict__ AO16, const unsigned short* __restrict__ W1T16,
    const float* __restrict__ SPKV, const float* __restrict__ BIASC,
    const float* __restrict__ SPK,
    const int* __restrict__ TGTA, const int* __restrict__ TGTD,
    int t, float* __restrict__ out)
{
  __shared__ float sm[8064];
  __shared__ float red_s[256], scp_s[256], sc_s[8], beta_s[8];
  int blk = blockIdx.x, tid = threadIdx.x;
  float* lacc = ST + S_LACC;
  if (blk < 8){
    int b = blk;
    float* gid_s = sm;           // 1152
    float* hd_s  = sm + 1152;    // 384
    float* ha_s  = sm + 1536;    // 750
    float* ac_s  = sm + 2286;    // 384
    float* xs    = sm + 2670;    // 384 (SCTX)
    for (int j = tid; j < 750; j += 256) ha_s[j] = ST[S_HASR + b*750 + j];
    for (int j = tid; j < 384; j += 256){
      ac_s[j] = ST[S_ACTX + b*384 + j];
      xs[j]   = ST[S_SCTX + b*384 + j];
    }
    __syncthreads();
    // GID = WD_IR @ sctx + GED(t)
    for (int r = tid; r < 1152; r += 256){
      const uint4* w4 = (const uint4*)(WD_IR + (size_t)r*384);
      float s = 0.f;
      #pragma unroll 4
      for (int kq = 0; kq < 48; kq++){
        uint4 w = w4[kq];
        const float* xp = xs + kq*8;
        s += bf2f((unsigned short)(w.x & 0xffff))*xp[0];
        s += bf2f((unsigned short)(w.x >> 16))   *xp[1];
        s += bf2f((unsigned short)(w.y & 0xffff))*xp[2];
        s += bf2f((unsigned short)(w.y >> 16))   *xp[3];
        s += bf2f((unsigned short)(w.z & 0xffff))*xp[4];
        s += bf2f((unsigned short)(w.z >> 16))   *xp[5];
        s += bf2f((unsigned short)(w.w & 0xffff))*xp[6];
        s += bf2f((unsigned short)(w.w >> 16))   *xp[7];
      }
      gid_s[r] = s + bf2f(GED16[(size_t)t*9216 + b*1152 + r]);
    }
    __syncthreads();
    float np = 0.f;
    for (int d = tid; d < 384; d += 256){
      int base = b*1152 + d;
      float rr = sigmf(gid_s[d]       + ST[S_GHD + base]);
      float zz = sigmf(gid_s[d + 384] + ST[S_GHD + base + 384]);
      float nn = tanhf(gid_s[d + 768] + rr*ST[S_GHD + base + 768]);
      float h = (1.f - zz)*nn + zz*hdc[b*384 + d];
      hd_s[d] = h; hdn[b*384 + d] = h; np += h*h;
    }
    red_s[tid] = np; __syncthreads();
    for (int k = 128; k > 0; k >>= 1){ if (tid < k) red_s[tid] += red_s[tid + k]; __syncthreads(); }
    float hn = sqrtf(red_s[0]);
    int sg = tid >> 5, si = tid & 31;
    float ps = 0.f;
    for (int j = si; j < 384; j += 32) ps += SPK[((size_t)(b*8 + sg))*384 + j]*hd_s[j];
    scp_s[tid] = ps; __syncthreads();
    if (tid < 8){
      float s = 0.f;
      for (int q = 0; q < 32; q++) s += scp_s[tid*32 + q];
      sc_s[tid] = s / (hn * ST[S_INVN + b*8 + tid]);
    }
    __syncthreads();
    if (tid == 0){
      float mx = -1e30f;
      for (int s2 = 0; s2 < 8; s2++) mx = fmaxf(mx, sc_s[s2]);
      float sum = 0.f;
      for (int s2 = 0; s2 < 8; s2++){ float e = __expf(sc_s[s2] - mx); beta_s[s2] = e; sum += e; }
      float inv = 1.f/sum;
      for (int s2 = 0; s2 < 8; s2++) beta_s[s2] *= inv;
      int td = TGTD[b*T_TXT + t];
      if (td != -100){ atomicAdd(&lacc[2], beta_s[td]); atomicAdd(&lacc[3], 1.f); }
    }
    __syncthreads();
    if (tid < 8) out[122880 + ((size_t)(b*T_TXT + t))*8 + tid] = beta_s[tid];
    if (tid < VOCAB){
      float lg = BIASC[tid];
      for (int d = 0; d < 384; d++) lg += ac_s[d]*bf2f(AO16[(size_t)d*VOCAB + tid]);
      for (int l = 0; l < 750; l++) lg += ha_s[l]*bf2f(W1T16[(size_t)l*VOCAB + tid]);
      #pragma unroll
      for (int s2 = 0; s2 < 8; s2++) lg += beta_s[s2]*SPKV[(size_t)(b*8 + s2)*VOCAB + tid];
      out[((size_t)(b*T_TXT + t))*VOCAB + tid] = lg;
      int ta = TGTA[b*T_TXT + t];
      if (ta == tid) atomicAdd(&lacc[0], lg);
      if (tid == 0 && ta != -100) atomicAdd(&lacc[1], 1.f);
    }
  } else if (t + 1 < T_TXT){
    gemv8(WA_I, 2250, 384, ST + S_ACTX, GEA16 + (size_t)(t+1)*18000, 0, nullptr,
          ST + S_GIA, blk - 8, sm);
  }
}

__global__ void loss_final_k(const float* __restrict__ lacc, float* __restrict__ out){
  if (threadIdx.x == 0 && blockIdx.x == 0){
    float la = lacc[0]/fmaxf(lacc[1], 1.f);
    float ld = lacc[2]/fmaxf(lacc[3], 1.f);
    out[139264] = -(la + ld);
  }
}

// ---------------------------------------------------------------------------
extern "C" void kernel_launch(void* const* d_in, const int* in_sizes, int n_in,
                              void* d_out, int out_size, void* d_ws, size_t ws_size,
                              hipStream_t stream)
{
  (void)in_sizes; (void)n_in; (void)out_size; (void)ws_size;
  float* ws  = (float*)d_ws;
  float* out = (float*)d_out;

  const float* IN0   = (const float*)d_in[0];
  const float* SPK   = (const float*)d_in[1];
  const float* C1W   = (const float*)d_in[2];
  const float* C1B   = (const float*)d_in[3];
  const float* C2W   = (const float*)d_in[4];
  const float* C2B   = (const float*)d_in[5];
  const float* LAQ   = (const float*)d_in[30];
  const float* LAK   = (const float*)d_in[31];
  const float* LAV   = (const float*)d_in[32];
  const float* LAIB  = (const float*)d_in[33];
  const float* LAOW  = (const float*)d_in[34];
  const float* LAOB  = (const float*)d_in[35];
  const float* EMB   = (const float*)d_in[36];
  const float* AWIH  = (const float*)d_in[37];
  const float* AWHH  = (const float*)d_in[38];
  const float* ABIH  = (const float*)d_in[39];
  const float* ABHH  = (const float*)d_in[40];
  const float* DWIH  = (const float*)d_in[41];
  const float* DWHH  = (const float*)d_in[42];
  const float* DBIH  = (const float*)d_in[43];
  const float* DBHH  = (const float*)d_in[44];
  const float* AOW   = (const float*)d_in[45];
  const float* AOB   = (const float*)d_in[46];
  const float* D2AW  = (const float*)d_in[47];
  const float* D2AB  = (const float*)d_in[48];
  const float* H2AW  = (const float*)d_in[49];
  const float* H2AB  = (const float*)d_in[50];
  const int*   TGTA  = (const int*)d_in[51];
  const int*   TGTD  = (const int*)d_in[52];

  // ---- workspace layout (float offsets) ----
  const size_t O_X   = 0;
  const size_t O_EA  = 2304000;
  const size_t O_ED  = 4608000;
  const size_t O_ST  = 6912000;   // ST_SIZE floats of state (zeroed each call)
  const size_t O_SCR = 7014200;
  // encoder scratch
  const size_t S_QKV = O_SCR;
  const size_t S_KT  = O_SCR + 6912000;
  const size_t S_CTX = O_SCR + 9216000;
  const size_t S_Y   = O_SCR + 11520000;
  const size_t S_H   = O_SCR + 13824000;
  const size_t X1T   = S_KT;
  const size_t P1    = S_H;
  const size_t P2    = S_QKV;
  // decode precompute overlay (written after encoder finishes)
  const size_t WIHAT_A16 = O_SCR + 0;        // 384x2250 bf16
  const size_t WHHT_A16  = O_SCR + 432000;   // 750x2250 bf16
  const size_t WHHT_D16  = O_SCR + 1496934;  // 384x1152 bf16
  const size_t EAT16o    = O_SCR + 1718118;  // 8x384x750 bf16
  const size_t EDT16o    = O_SCR + 2870118;  // 8x384x750 bf16
  const size_t AO16o     = O_SCR + 4022118;  // 384x60 bf16
  const size_t W1T16o    = O_SCR + 4033638;  // 750x60 bf16
  const size_t SPKVo     = O_SCR + 4056138;  // 64x60 fp32
  const size_t BIASCo    = O_SCR + 4059978;  // 60 fp32
  const size_t H2AWTo    = O_SCR + 4060038;  // 750x384 fp32
  const size_t D2ATfo    = O_SCR + 4348038;  // 384x384 fp32
  const size_t W1fo      = O_SCR + 4495494;  // 60x750 fp32
  const size_t W2fo      = O_SCR + 4540494;  // 60x384 fp32
  const size_t EMBTo     = O_SCR + 4563534;  // 2048x384 fp32
  const size_t GEA16o    = O_SCR + 5349966;  // 2048x2250 bf16
  const size_t GED16o    = O_SCR + 7653966;  // 2048x1152 bf16
  const size_t WDIR16o   = O_SCR + 8833614;  // 1152x384 bf16 row-major

  // 1) zero decode state + loss accumulators
  hipMemsetAsync((void*)(ws + O_ST), 0, ST_SIZE*sizeof(float), stream);

  // 2) convs via im2col + GEMM
  im2col1<<<dim3(1500,8), 256, 0, stream>>>(IN0, ws + P1);
  gemm_k<1,0><<<dim3(6,94), 256, 0, stream>>>(ws+P1, 240, C1W, 240, C1B, nullptr, ws+X1T, 384, 12000, 384, 240);
  im2col2<<<dim3(750,8), 384, 0, stream>>>(ws+X1T, ws+P2);
  gemm_k<1,0><<<dim3(6,47), 256, 0, stream>>>(ws+P2, 1152, C2W, 1152, C2B, nullptr, ws+O_X, 384, 6000, 384, 1152);

  hipMemcpyAsync(ws+O_EA, ws+O_X, 2304000*sizeof(float), hipMemcpyDeviceToDevice, stream);
  hipMemcpyAsync(ws+O_ED, ws+O_X, 2304000*sizeof(float), hipMemcpyDeviceToDevice, stream);

  // 3) encoder stacks
  auto enc_layer = [&](float* Xb, const float* qw, const float* qb, const float* ow,
                       const float* ob, const float* f1w, const float* f1b,
                       const float* f2w, const float* f2b,
                       const float* g1, const float* b1, const float* g2, const float* b2){
    gemm_k<0,0><<<dim3(18,47), 256, 0, stream>>>(Xb, 384, qw, 384, qb, nullptr, ws+S_QKV, 1152, 6000, 1152, 384);
    kt_k<<<dim3(3,24,32), dim3(32,8), 0, stream>>>(ws+S_QKV, ws+S_KT);
    attn_enc<<<dim3(47,4,8), 1024, 0, stream>>>(ws+S_QKV, ws+S_KT, ws+S_CTX);
    gemm_k<0,1><<<dim3(6,47), 256, 0, stream>>>(ws+S_CTX, 384, ow, 384, ob, Xb, ws+S_Y, 384, 6000, 384, 384);
    ln_k<<<6000, 128, 0, stream>>>(ws+S_Y, g1, b1);
    gemm_k<1,0><<<dim3(16,47), 256, 0, stream>>>(ws+S_Y, 384, f1w, 384, f1b, nullptr, ws+S_H, 1024, 6000, 1024, 384);
    gemm_k<0,1><<<dim3(6,47), 256, 0, stream>>>(ws+S_H, 1024, f2w, 1024, f2b, ws+S_Y, Xb, 384, 6000, 384, 1024);
    ln_k<<<6000, 128, 0, stream>>>(Xb, g2, b2);
  };
  for (int st = 0; st < 2; st++){
    int base = (st == 0) ? 6 : 18;
    float* Xb = ws + ((st == 0) ? O_EA : O_ED);
    const float* qkvw = (const float*)d_in[base+0];
    const float* qkvb = (const float*)d_in[base+1];
    const float* aow  = (const float*)d_in[base+2];
    const float* aob2 = (const float*)d_in[base+3];
    const float* f1w  = (const float*)d_in[base+4];
    const float* f1b  = (const float*)d_in[base+5];
    const float* f2w  = (const float*)d_in[base+6];
    const float* f2b  = (const float*)d_in[base+7];
    const float* g1   = (const float*)d_in[base+8];
    const float* b1   = (const float*)d_in[base+9];
    const float* g2   = (const float*)d_in[base+10];
    const float* b2   = (const float*)d_in[base+11];
    for (int l = 0; l < 2; l++){
      enc_layer(Xb, qkvw + (size_t)l*1152*384, qkvb + (size_t)l*1152,
                aow + (size_t)l*384*384, aob2 + (size_t)l*384,
                f1w + (size_t)l*1024*384, f1b + (size_t)l*1024,
                f2w + (size_t)l*384*1024, f2b + (size_t)l*384,
                g1 + (size_t)l*384, b1 + (size_t)l*384, g2 + (size_t)l*384, b2 + (size_t)l*384);
    }
  }

  // 4) decode precompute
  transpose_bf16_k<<<dim3(12,71), dim3(32,8), 0, stream>>>(AWIH, 768, 2250, 384, (unsigned short*)(ws+WIHAT_A16), 0, 0);
  transpose_bf16_k<<<dim3(24,71), dim3(32,8), 0, stream>>>(AWHH, 750, 2250, 750, (unsigned short*)(ws+WHHT_A16), 0, 0);
  transpose_bf16_k<<<dim3(12,36), dim3(32,8), 0, stream>>>(DWHH, 384, 1152, 384, (unsigned short*)(ws+WHHT_D16), 0, 0);
  convrow_k<<<1152, 384, 0, stream>>>(DWIH, 768, 384, (unsigned short*)(ws+WDIR16o));
  transpose_bf16_k<<<dim3(12,24,8), dim3(32,8), 0, stream>>>(ws+O_EA, 384, 750, 384, (unsigned short*)(ws+EAT16o), 288000, 288000);
  transpose_bf16_k<<<dim3(12,24,8), dim3(32,8), 0, stream>>>(ws+O_ED, 384, 750, 384, (unsigned short*)(ws+EDT16o), 288000, 288000);
  transpose_bf16_k<<<dim3(12,2),  dim3(32,8), 0, stream>>>(AOW, 384, 60, 384, (unsigned short*)(ws+AO16o), 0, 0);
  transpose_k<<<dim3(24,12), dim3(32,8), 0, stream>>>(H2AW, 750, 384, 750, ws+H2AWTo);
  transpose_k<<<dim3(12,12), dim3(32,8), 0, stream>>>(D2AW, 384, 384, 384, ws+D2ATfo);
  gemm_k<0,0,0,1><<<dim3(12,1), 256, 0, stream>>>(AOW, 384, ws+H2AWTo, 384, nullptr, nullptr, ws+W1fo, 750, 60, 750, 384);
  transpose_bf16_k<<<dim3(24,2), dim3(32,8), 0, stream>>>(ws+W1fo, 750, 60, 750, (unsigned short*)(ws+W1T16o), 0, 0);
  gemm_k<0,0,0,1><<<dim3(6,1), 256, 0, stream>>>(AOW, 384, ws+D2ATfo, 384, nullptr, nullptr, ws+W2fo, 384, 60, 384, 384);
  gemm_k<0,0,0,1><<<dim3(1,1), 256, 0, stream>>>(SPK, 384, ws+W2fo, 384, nullptr, nullptr, ws+SPKVo, 60, 64, 60, 384);
  biasc_k<<<1, 64, 0, stream>>>(AOB, H2AB, D2AB, AOW, ws+BIASCo);
  embed_k<<<2048, 384, 0, stream>>>(EMB, TGTA, ws+EMBTo);
  gemm_k<0,0,1><<<dim3(36,16), 256, 0, stream>>>(ws+EMBTo, 384, AWIH+384, 768, ABIH, nullptr, (float*)(ws+GEA16o), 2250, 2048, 2250, 384);
  gemm_k<0,0,1><<<dim3(18,16), 256, 0, stream>>>(ws+EMBTo, 384, DWIH+384, 768, DBIH, nullptr, (float*)(ws+GED16o), 1152, 2048, 1152, 384);
  vla_k<<<1500, 256, 0, stream>>>(ws+O_EA, LAV, LAIB, ws+O_ST+S_VLA);
  invn_k<<<64, 64, 0, stream>>>(SPK, ws+O_ST+S_INVN);
  init_gates_k<<<71, 256, 0, stream>>>((const unsigned short*)(ws+GEA16o), ABHH, ws+O_ST);

  // 5) decode loop: 3 kernel launches per step (launch = free grid barrier)
  float* ST = ws + O_ST;
  for (int t = 0; t < T_TXT; t++){
    float* acur = ST + ((t & 1) ? S_ATT1 : S_ATT0);
    float* anxt = ST + ((t & 1) ? S_ATT0 : S_ATT1);
    float* hdc  = ST + ((t & 1) ? S_HD1 : S_HD0);
    float* hdn  = ST + ((t & 1) ? S_HD0 : S_HD1);
    ph1_k<<<164, 256, 0, stream>>>(ST, acur, anxt, hdc,
        (const unsigned short*)(ws+WHHT_D16), DBHH, LAQ, LAK, LAIB, LAOW, LAOB);
    ph2_k<<<199, 256, 0, stream>>>(ST, anxt,
        (const unsigned short*)(ws+EAT16o), (const unsigned short*)(ws+EDT16o),
        (const unsigned short*)(ws+WHHT_A16), ABHH);
    ph3_k<<<79, 256, 0, stream>>>(ST, hdc, hdn,
        (const unsigned short*)(ws+WDIR16o), (const unsigned short*)(ws+GED16o),
        (const unsigned short*)(ws+WIHAT_A16), (const unsigned short*)(ws+GEA16o),
        (const unsigned short*)(ws+AO16o), (const unsigned short*)(ws+W1T16o),
        ws+SPKVo, ws+BIASCo, SPK, TGTA, TGTD, t, out);
  }
  loss_final_k<<<1, 64, 0, stream>>>(ws+O_ST+S_LACC, out);
}